// Round 18
// baseline (80.209 us; speedup 1.0000x reference)
//
#include <hip/hip_runtime.h>

// GaborBasis: out[b,t,r] = window_norm * cos(z·K[r] + phi[r]),
//   window = exp(-max(|z|^2+|mu_r|^2-2 z·mu_r,0)/(2 sigma_r^2)), normalized over r.
// fp16 hi/lo 3-term split MFMA (16x16x32); v_fract+v_cos epilogue.
// Round 18: r16's A-ping-pong was right but the allocator spilled at VGPR=128
// (targeting 4 waves/SIMD occupancy that grid=1 block/CU can never use).
// Fix: __launch_bounds__(512, 1) -> VGPR cap 256 (real occupancy unchanged:
// 8 waves/block = 2/SIMD). A+B both ping-ponged => steady-state clusters have
// zero serial operand waits. Base otherwise r17: 64 rows x 1024 cols/block,
// disjoint 128-col wave slices, fused prep+split, block-local norm.

typedef _Float16 f16x8 __attribute__((ext_vector_type(8)));
typedef float f32x4 __attribute__((ext_vector_type(4)));

#define M_DIM 16384
#define R_DIM 1024
#define INV2PI 0.15915494309189535f

// ---------------- prep+split fused ----------------
// blocks 0..4095: zsq; 4096..4351: mu stats; 4352..4607: mu/K fragment split.
__global__ void gabor_prep(const float* __restrict__ z, const float* __restrict__ mu,
                           const float* __restrict__ Kmat,
                           const float* __restrict__ ls, const float* __restrict__ phi,
                           float* __restrict__ zsq, float* __restrict__ musq,
                           float* __restrict__ inv2s2, float* __restrict__ phirev,
                           _Float16* __restrict__ muf, _Float16* __restrict__ kf) {
    const int bid = blockIdx.x;
    if (bid < 4352) {
        const int lane = threadIdx.x & 63;
        const int wv = threadIdx.x >> 6;
        if (bid < 4096) {
            const int row = bid * 4 + wv;
            float4 v = *(const float4*)(z + (size_t)row * 256 + lane * 4);
            float s = v.x * v.x + v.y * v.y + v.z * v.z + v.w * v.w;
#pragma unroll
            for (int sh = 1; sh < 64; sh <<= 1) s += __shfl_xor(s, sh, 64);
            if (lane == 0) zsq[row] = s;
        } else {
            const int row = (bid - 4096) * 4 + wv;
            float4 v = *(const float4*)(mu + (size_t)row * 256 + lane * 4);
            float s = v.x * v.x + v.y * v.y + v.z * v.z + v.w * v.w;
#pragma unroll
            for (int sh = 1; sh < 64; sh <<= 1) s += __shfl_xor(s, sh, 64);
            if (lane == 0) {
                musq[row] = s;
                float e = expf(ls[row]);
                inv2s2[row] = 1.0f / (2.0f * (e * e + 1e-8f));
                phirev[row] = phi[row] * INV2PI;
            }
        }
        return;
    }
    // fragment split: 16x16x32 MFMA order. Per matrix: [sub=col/16][ks=k/32] x 1024
    // halves: hi at lane*8, lo at 512+lane*8, lane = (col&15) | ((k>>3 & 3)<<4).
    const int t = (bid - 4352) * 256 + threadIdx.x;   // 0..65535
    const float* src; _Float16* dst; int item;
    if (t < 32768) { item = t;          src = mu;   dst = muf; }
    else           { item = t - 32768;  src = Kmat; dst = kf; }
    const int sub = item >> 9, rem = item & 511;      // sub 0..63
    const int ks = rem >> 6, l = rem & 63;
    const int col = sub * 16 + (l & 15);
    const int k0 = ks * 32 + (l >> 4) * 8;
    const float* sp = src + (size_t)col * 256 + k0;
    float v[8];
    *(float4*)&v[0] = *(const float4*)(sp);
    *(float4*)&v[4] = *(const float4*)(sp + 4);
    f16x8 hi, lo;
#pragma unroll
    for (int j = 0; j < 8; ++j) {
        _Float16 h = (_Float16)v[j];
        hi[j] = h;
        lo[j] = (_Float16)(v[j] - (float)h);
    }
    _Float16* d = dst + (size_t)(sub * 8 + ks) * 1024;
    *(f16x8*)(d + l * 8) = hi;
    *(f16x8*)(d + 512 + l * 8) = lo;
}

// ---------------- main: 256 blocks x 512 thr (8 waves). Block = 64 rows x 1024 cols. ----------------
// Wave = all 64 rows x disjoint 128-col slice; 4 chunks of 32 cols (rotated per
// block); 48-MFMA clusters; barrier-free K loop; block-local normalization.
template <bool PRE>
__global__ __launch_bounds__(512, 1) void gabor_main(
    const float* __restrict__ z, const float* __restrict__ mu, const float* __restrict__ Kmat,
    const _Float16* __restrict__ muf, const _Float16* __restrict__ kf,
    const float* __restrict__ zsq, const float* __restrict__ musq,
    const float* __restrict__ inv2s2, const float* __restrict__ phirev,
    float* __restrict__ out) {
    __shared__ _Float16 sA[32768];      // [sub 0..3][ks 0..7][1024]: hi lane*8, lo 512+lane*8 (64KB)
    __shared__ float sZsq[64];
    __shared__ float sRow[8][64];
    __shared__ float sInvN[64];

    const int tid = threadIdx.x;
    const int bid = blockIdx.x;
    const int rbase = bid * 64;

    // ---- stage A panel (64 rows x 256 k, hi/lo) ONCE, from raw fp32 z ----
#pragma unroll
    for (int j = 0; j < 4; ++j) {
        const int it = tid + j * 512;        // 0..2047: sub(4) x ks(8) x lane(64)
        const int sub = it >> 9, rem = it & 511;
        const int ks = rem >> 6, l = rem & 63;
        const int row = rbase + sub * 16 + (l & 15);
        const float* sp = z + (size_t)row * 256 + ks * 32 + (l >> 4) * 8;
        float v[8];
        *(float4*)&v[0] = *(const float4*)(sp);
        *(float4*)&v[4] = *(const float4*)(sp + 4);
        f16x8 hi, lo;
#pragma unroll
        for (int q = 0; q < 8; ++q) {
            _Float16 h = (_Float16)v[q];
            hi[q] = h; lo[q] = (_Float16)(v[q] - (float)h);
        }
        const int o = (sub * 8 + ks) * 1024 + l * 8;
        *(f16x8*)&sA[o] = hi;
        *(f16x8*)&sA[o + 512] = lo;
    }
    if (tid < 64) sZsq[tid] = zsq[rbase + tid];
    __syncthreads();                       // the ONLY barrier before the tail

    const int lane = tid & 63;
    const int wc = tid >> 6;               // 0..7 : this wave's 128-col slice (disjoint)
    const int lr = lane & 15, lg = lane >> 4;

    float rs[16];
#pragma unroll
    for (int i = 0; i < 16; ++i) rs[i] = 0.f;

    // Ping-pong register sets (parity = ks&1, compile-time in the unrolled loop):
    f16x8 B[2][8];      // [muH0, muL0, muH1, muL1, kH0, kL0, kH1, kL1]
    f16x8 aH[2][4], aL[2][4];

    auto loadB = [&](int buf, int cc, int ks) {
        if constexpr (PRE) {
            const size_t sb = (size_t)((wc * 8 + cc * 2) * 8 + ks) * 1024 + lane * 8;
            const _Float16* mp = muf + sb;
            B[buf][0] = *(const f16x8*)(mp);
            B[buf][1] = *(const f16x8*)(mp + 512);
            B[buf][2] = *(const f16x8*)(mp + 8192);
            B[buf][3] = *(const f16x8*)(mp + 8192 + 512);
            const _Float16* kp = kf + sb;
            B[buf][4] = *(const f16x8*)(kp);
            B[buf][5] = *(const f16x8*)(kp + 512);
            B[buf][6] = *(const f16x8*)(kp + 8192);
            B[buf][7] = *(const f16x8*)(kp + 8192 + 512);
        } else {
#pragma unroll
            for (int n = 0; n < 2; ++n) {
                const int col = wc * 128 + cc * 32 + n * 16 + lr;
                const int k0 = ks * 32 + lg * 8;
                float v[8];
                const float* sp = mu + (size_t)col * 256 + k0;
                *(float4*)&v[0] = *(const float4*)(sp);
                *(float4*)&v[4] = *(const float4*)(sp + 4);
#pragma unroll
                for (int q = 0; q < 8; ++q) {
                    _Float16 h = (_Float16)v[q];
                    B[buf][n * 2][q] = h; B[buf][n * 2 + 1][q] = (_Float16)(v[q] - (float)h);
                }
                const float* sp2 = Kmat + (size_t)col * 256 + k0;
                *(float4*)&v[0] = *(const float4*)(sp2);
                *(float4*)&v[4] = *(const float4*)(sp2 + 4);
#pragma unroll
                for (int q = 0; q < 8; ++q) {
                    _Float16 h = (_Float16)v[q];
                    B[buf][4 + n * 2][q] = h; B[buf][4 + n * 2 + 1][q] = (_Float16)(v[q] - (float)h);
                }
            }
        }
    };
    auto loadA = [&](int set, int ks) {
#pragma unroll
        for (int m = 0; m < 4; ++m) {
            const int o = (m * 8 + ks) * 1024 + lane * 8;
            aH[set][m] = *(const f16x8*)&sA[o];
            aL[set][m] = *(const f16x8*)&sA[o + 512];
        }
    };

    // chunk order rotated per block (kept from r17; neutral but harmless)
    const int crot = bid & 3;
    loadA(0, 0);
    loadB(0, crot, 0);

#pragma unroll 1
    for (int cc = 0; cc < 4; ++cc) {
        const int ccr = (cc + crot) & 3;
        const int ccn = (cc + 1 + crot) & 3;
        f32x4 accC[4][2], accP[4][2];
#pragma unroll
        for (int m = 0; m < 4; ++m)
#pragma unroll
            for (int n = 0; n < 2; ++n) {
                accC[m][n] = (f32x4){0.f, 0.f, 0.f, 0.f};
                accP[m][n] = (f32x4){0.f, 0.f, 0.f, 0.f};
            }

#pragma unroll
        for (int ks = 0; ks < 8; ++ks) {
            const int cur = ks & 1;
            const int nxt = cur ^ 1;
            // issue next iteration's operands (A ds_reads + B global loads) NOW;
            // they complete during this 48-MFMA cluster (~930 cyc >> L2/LDS latency)
            if (ks < 7) {
                loadA(nxt, ks + 1);
                loadB(nxt, ccr, ks + 1);
            } else if (cc < 3) {
                loadA(nxt, 0);
                loadB(nxt, ccn, 0);        // additionally covered by chunk epilogue
            }
            __builtin_amdgcn_sched_barrier(0);

            __builtin_amdgcn_s_setprio(1);
            // 16 independent acc chains, 48 MFMA on current-parity operands
#pragma unroll
            for (int m = 0; m < 4; ++m)
#pragma unroll
                for (int n = 0; n < 2; ++n)
                    accC[m][n] = __builtin_amdgcn_mfma_f32_16x16x32_f16(aH[cur][m], B[cur][n * 2], accC[m][n], 0, 0, 0);
#pragma unroll
            for (int m = 0; m < 4; ++m)
#pragma unroll
                for (int n = 0; n < 2; ++n)
                    accP[m][n] = __builtin_amdgcn_mfma_f32_16x16x32_f16(aH[cur][m], B[cur][4 + n * 2], accP[m][n], 0, 0, 0);
#pragma unroll
            for (int m = 0; m < 4; ++m)
#pragma unroll
                for (int n = 0; n < 2; ++n)
                    accC[m][n] = __builtin_amdgcn_mfma_f32_16x16x32_f16(aH[cur][m], B[cur][n * 2 + 1], accC[m][n], 0, 0, 0);
#pragma unroll
            for (int m = 0; m < 4; ++m)
#pragma unroll
                for (int n = 0; n < 2; ++n)
                    accP[m][n] = __builtin_amdgcn_mfma_f32_16x16x32_f16(aH[cur][m], B[cur][4 + n * 2 + 1], accP[m][n], 0, 0, 0);
#pragma unroll
            for (int m = 0; m < 4; ++m)
#pragma unroll
                for (int n = 0; n < 2; ++n)
                    accC[m][n] = __builtin_amdgcn_mfma_f32_16x16x32_f16(aL[cur][m], B[cur][n * 2], accC[m][n], 0, 0, 0);
#pragma unroll
            for (int m = 0; m < 4; ++m)
#pragma unroll
                for (int n = 0; n < 2; ++n)
                    accP[m][n] = __builtin_amdgcn_mfma_f32_16x16x32_f16(aL[cur][m], B[cur][4 + n * 2], accP[m][n], 0, 0, 0);
            __builtin_amdgcn_s_setprio(0);
        }

        // ---- per-chunk epilogue: w = __expf, cos via v_fract+v_cos (revolutions) ----
#pragma unroll
        for (int m = 0; m < 4; ++m)
#pragma unroll
            for (int n = 0; n < 2; ++n) {
                const int col = wc * 128 + ccr * 32 + n * 16 + lr;
                const float msq = musq[col], il2 = inv2s2[col], prv = phirev[col];
                f32x4 ccv = accC[m][n], pp = accP[m][n];
#pragma unroll
                for (int rg = 0; rg < 4; ++rg) {
                    const int rowl = m * 16 + lg * 4 + rg;
                    float dsq = fmaxf(sZsq[rowl] + msq - 2.0f * ccv[rg], 0.f);
                    float w = __expf(-dsq * il2);
                    float ph = __builtin_fmaf(pp[rg], INV2PI, prv);
                    float r, cs;
                    asm("v_fract_f32 %0, %1" : "=v"(r) : "v"(ph));
                    asm("v_cos_f32 %0, %1" : "=v"(cs) : "v"(r));
                    out[(size_t)(rbase + rowl) * R_DIM + col] = w * cs;
                    rs[m * 4 + rg] += w;
                }
            }
    }

    // ---- block-local row sums -> normalize own 64x1024 tile ----
#pragma unroll
    for (int i = 0; i < 16; ++i) {
#pragma unroll
        for (int sh = 1; sh < 16; sh <<= 1) rs[i] += __shfl_xor(rs[i], sh, 64);
    }
    if (lr == 0) {
#pragma unroll
        for (int m = 0; m < 4; ++m)
#pragma unroll
            for (int rg = 0; rg < 4; ++rg)
                sRow[wc][m * 16 + lg * 4 + rg] = rs[m * 4 + rg];
    }
    __syncthreads();
    if (tid < 64) {
        float s = 0.f;
#pragma unroll
        for (int w8 = 0; w8 < 8; ++w8) s += sRow[w8][tid];
        sInvN[tid] = 1.0f / fmaxf(s, 1e-6f);
    }
    __threadfence_block();
    __syncthreads();

    float4* obase = (float4*)(out + (size_t)rbase * R_DIM);
#pragma unroll 4
    for (int j = 0; j < 32; ++j) {
        const int idx = j * 512 + tid;        // 0..16383 float4s
        const int row = idx >> 8, c4 = idx & 255;
        const float inv = sInvN[row];
        float4 v = obase[row * 256 + c4];
        v.x *= inv; v.y *= inv; v.z *= inv; v.w *= inv;
        obase[row * 256 + c4] = v;
    }
}

extern "C" void kernel_launch(void* const* d_in, const int* in_sizes, int n_in,
                              void* d_out, int out_size, void* d_ws, size_t ws_size,
                              hipStream_t stream) {
    const float* z    = (const float*)d_in[0];
    const float* mu   = (const float*)d_in[1];
    const float* Kmat = (const float*)d_in[2];
    const float* ls   = (const float*)d_in[3];
    const float* phi  = (const float*)d_in[4];
    float* out = (float*)d_out;
    float* ws = (float*)d_ws;
    float* zsq      = ws;                        // 16384
    float* musq     = ws + 16384;                // 1024
    float* i2s      = ws + 17408;                // 1024
    float* phirev   = ws + 18432;                // 1024
    _Float16* muf = (_Float16*)(ws + 150528);    // 1024*512 halves (16x16 fragment order)
    _Float16* kf  = muf + 524288;                // 1024*512
    const bool pre = ws_size >= 2700000ull;      // floats + 2x1MB fragment buffers

    // one fused prep kernel: zsq + mu stats (+ fragment split when pre)
    hipLaunchKernelGGL(gabor_prep, dim3(pre ? 4608 : 4352), dim3(256), 0, stream,
                       z, mu, Kmat, ls, phi, zsq, musq, i2s, phirev, muf, kf);
    if (pre) {
        hipLaunchKernelGGL(gabor_main<true>, dim3(M_DIM / 64), dim3(512), 0, stream,
                           z, mu, Kmat, muf, kf, zsq, musq, i2s, phirev, out);
    } else {
        hipLaunchKernelGGL(gabor_main<false>, dim3(M_DIM / 64), dim3(512), 0, stream,
                           z, mu, Kmat, muf, kf, zsq, musq, i2s, phirev, out);
    }
}

// Round 19
// 76.670 us; speedup vs baseline: 1.0462x; 1.0462x over previous
//
#include <hip/hip_runtime.h>

// GaborBasis: out[b,t,r] = window_norm * cos(z·K[r] + phi[r]),
//   window = exp(-max(|z|^2+|mu_r|^2-2 z·mu_r,0)/(2 sigma_r^2)), normalized over r.
// fp16 hi/lo 3-term split MFMA (16x16x32); v_fract+v_cos epilogue.
// Round 19: r18 confirmed A-ping-pong can't fit registers (cap 128, spilled).
// r17's addr-rotation was flat -> the stall is TIME-coupled: both waves/SIMD
// run identical streams and hit waitcnt points simultaneously. Fix: stagger
// the second wave of each SIMD by ~half a 48-MFMA cluster via s_sleep once
// (loop is barrier-free so the offset persists) -> one wave's operand-wait
// gap overlaps the other's MFMA burst. Everything else identical to r17.

typedef _Float16 f16x8 __attribute__((ext_vector_type(8)));
typedef float f32x4 __attribute__((ext_vector_type(4)));

#define M_DIM 16384
#define R_DIM 1024
#define INV2PI 0.15915494309189535f

// ---------------- prep+split fused ----------------
// blocks 0..4095: zsq; 4096..4351: mu stats; 4352..4607: mu/K fragment split.
__global__ void gabor_prep(const float* __restrict__ z, const float* __restrict__ mu,
                           const float* __restrict__ Kmat,
                           const float* __restrict__ ls, const float* __restrict__ phi,
                           float* __restrict__ zsq, float* __restrict__ musq,
                           float* __restrict__ inv2s2, float* __restrict__ phirev,
                           _Float16* __restrict__ muf, _Float16* __restrict__ kf) {
    const int bid = blockIdx.x;
    if (bid < 4352) {
        const int lane = threadIdx.x & 63;
        const int wv = threadIdx.x >> 6;
        if (bid < 4096) {
            const int row = bid * 4 + wv;
            float4 v = *(const float4*)(z + (size_t)row * 256 + lane * 4);
            float s = v.x * v.x + v.y * v.y + v.z * v.z + v.w * v.w;
#pragma unroll
            for (int sh = 1; sh < 64; sh <<= 1) s += __shfl_xor(s, sh, 64);
            if (lane == 0) zsq[row] = s;
        } else {
            const int row = (bid - 4096) * 4 + wv;
            float4 v = *(const float4*)(mu + (size_t)row * 256 + lane * 4);
            float s = v.x * v.x + v.y * v.y + v.z * v.z + v.w * v.w;
#pragma unroll
            for (int sh = 1; sh < 64; sh <<= 1) s += __shfl_xor(s, sh, 64);
            if (lane == 0) {
                musq[row] = s;
                float e = expf(ls[row]);
                inv2s2[row] = 1.0f / (2.0f * (e * e + 1e-8f));
                phirev[row] = phi[row] * INV2PI;
            }
        }
        return;
    }
    // fragment split: 16x16x32 MFMA order. Per matrix: [sub=col/16][ks=k/32] x 1024
    // halves: hi at lane*8, lo at 512+lane*8, lane = (col&15) | ((k>>3 & 3)<<4).
    const int t = (bid - 4352) * 256 + threadIdx.x;   // 0..65535
    const float* src; _Float16* dst; int item;
    if (t < 32768) { item = t;          src = mu;   dst = muf; }
    else           { item = t - 32768;  src = Kmat; dst = kf; }
    const int sub = item >> 9, rem = item & 511;      // sub 0..63
    const int ks = rem >> 6, l = rem & 63;
    const int col = sub * 16 + (l & 15);
    const int k0 = ks * 32 + (l >> 4) * 8;
    const float* sp = src + (size_t)col * 256 + k0;
    float v[8];
    *(float4*)&v[0] = *(const float4*)(sp);
    *(float4*)&v[4] = *(const float4*)(sp + 4);
    f16x8 hi, lo;
#pragma unroll
    for (int j = 0; j < 8; ++j) {
        _Float16 h = (_Float16)v[j];
        hi[j] = h;
        lo[j] = (_Float16)(v[j] - (float)h);
    }
    _Float16* d = dst + (size_t)(sub * 8 + ks) * 1024;
    *(f16x8*)(d + l * 8) = hi;
    *(f16x8*)(d + 512 + l * 8) = lo;
}

// ---------------- main: 256 blocks x 512 thr (8 waves). Block = 64 rows x 1024 cols. ----------------
// Wave = all 64 rows x disjoint 128-col slice; 4 chunks of 32 cols (rotated per
// block); 48-MFMA clusters; barrier-free K loop; block-local normalization.
template <bool PRE>
__global__ __launch_bounds__(512, 2) void gabor_main(
    const float* __restrict__ z, const float* __restrict__ mu, const float* __restrict__ Kmat,
    const _Float16* __restrict__ muf, const _Float16* __restrict__ kf,
    const float* __restrict__ zsq, const float* __restrict__ musq,
    const float* __restrict__ inv2s2, const float* __restrict__ phirev,
    float* __restrict__ out) {
    __shared__ _Float16 sA[32768];      // [sub 0..3][ks 0..7][1024]: hi lane*8, lo 512+lane*8 (64KB)
    __shared__ float sZsq[64];
    __shared__ float sRow[8][64];
    __shared__ float sInvN[64];

    const int tid = threadIdx.x;
    const int bid = blockIdx.x;
    const int rbase = bid * 64;

    // ---- stage A panel (64 rows x 256 k, hi/lo) ONCE, from raw fp32 z ----
#pragma unroll
    for (int j = 0; j < 4; ++j) {
        const int it = tid + j * 512;        // 0..2047: sub(4) x ks(8) x lane(64)
        const int sub = it >> 9, rem = it & 511;
        const int ks = rem >> 6, l = rem & 63;
        const int row = rbase + sub * 16 + (l & 15);
        const float* sp = z + (size_t)row * 256 + ks * 32 + (l >> 4) * 8;
        float v[8];
        *(float4*)&v[0] = *(const float4*)(sp);
        *(float4*)&v[4] = *(const float4*)(sp + 4);
        f16x8 hi, lo;
#pragma unroll
        for (int q = 0; q < 8; ++q) {
            _Float16 h = (_Float16)v[q];
            hi[q] = h; lo[q] = (_Float16)(v[q] - (float)h);
        }
        const int o = (sub * 8 + ks) * 1024 + l * 8;
        *(f16x8*)&sA[o] = hi;
        *(f16x8*)&sA[o + 512] = lo;
    }
    if (tid < 64) sZsq[tid] = zsq[rbase + tid];
    __syncthreads();                       // the ONLY barrier before the tail

    const int lane = tid & 63;
    const int wc = tid >> 6;               // 0..7 : this wave's 128-col slice (disjoint)
    const int lr = lane & 15, lg = lane >> 4;

    // time-stagger: second wave of each SIMD (round-robin wave->SIMD => wc>=4)
    // sleeps ~448 cyc once; with no barriers below, the half-cluster phase
    // offset persists so paired waves' stall/MFMA phases interleave.
    if (wc >= 4) __builtin_amdgcn_s_sleep(7);

    float rs[16];
#pragma unroll
    for (int i = 0; i < 16; ++i) rs[i] = 0.f;

    // B register sets: [mu0H, mu0L, mu1H, mu1L, k0H, k0L, k1H, k1L] x2 (ping-pong)
    f16x8 B[2][8];
    auto loadB = [&](int buf, int cc, int ks) {
        if constexpr (PRE) {
            const size_t sb = (size_t)((wc * 8 + cc * 2) * 8 + ks) * 1024 + lane * 8;
            const _Float16* mp = muf + sb;
            B[buf][0] = *(const f16x8*)(mp);
            B[buf][1] = *(const f16x8*)(mp + 512);
            B[buf][2] = *(const f16x8*)(mp + 8192);
            B[buf][3] = *(const f16x8*)(mp + 8192 + 512);
            const _Float16* kp = kf + sb;
            B[buf][4] = *(const f16x8*)(kp);
            B[buf][5] = *(const f16x8*)(kp + 512);
            B[buf][6] = *(const f16x8*)(kp + 8192);
            B[buf][7] = *(const f16x8*)(kp + 8192 + 512);
        } else {
#pragma unroll
            for (int n = 0; n < 2; ++n) {
                const int col = wc * 128 + cc * 32 + n * 16 + lr;
                const int k0 = ks * 32 + lg * 8;
                float v[8];
                const float* sp = mu + (size_t)col * 256 + k0;
                *(float4*)&v[0] = *(const float4*)(sp);
                *(float4*)&v[4] = *(const float4*)(sp + 4);
#pragma unroll
                for (int q = 0; q < 8; ++q) {
                    _Float16 h = (_Float16)v[q];
                    B[buf][n * 2][q] = h; B[buf][n * 2 + 1][q] = (_Float16)(v[q] - (float)h);
                }
                const float* sp2 = Kmat + (size_t)col * 256 + k0;
                *(float4*)&v[0] = *(const float4*)(sp2);
                *(float4*)&v[4] = *(const float4*)(sp2 + 4);
#pragma unroll
                for (int q = 0; q < 8; ++q) {
                    _Float16 h = (_Float16)v[q];
                    B[buf][4 + n * 2][q] = h; B[buf][4 + n * 2 + 1][q] = (_Float16)(v[q] - (float)h);
                }
            }
        }
    };

    // chunk order rotated per block (kept from r17; neutral but harmless)
    const int crot = bid & 3;
    loadB(0, crot, 0);

#pragma unroll 1
    for (int cc = 0; cc < 4; ++cc) {
        const int ccr = (cc + crot) & 3;
        const int ccn = (cc + 1 + crot) & 3;
        f32x4 accC[4][2], accP[4][2];
#pragma unroll
        for (int m = 0; m < 4; ++m)
#pragma unroll
            for (int n = 0; n < 2; ++n) {
                accC[m][n] = (f32x4){0.f, 0.f, 0.f, 0.f};
                accP[m][n] = (f32x4){0.f, 0.f, 0.f, 0.f};
            }

#pragma unroll
        for (int ks = 0; ks < 8; ++ks) {
            const int cur = ks & 1;
            const int nxt = cur ^ 1;
            // A fragments from LDS: all 4 row-subs (lane-linear, conflict-free)
            f16x8 aH[4], aL[4];
#pragma unroll
            for (int m = 0; m < 4; ++m) {
                const int o = (m * 8 + ks) * 1024 + lane * 8;
                aH[m] = *(const f16x8*)&sA[o];
                aL[m] = *(const f16x8*)&sA[o + 512];
            }
            // ping-pong B prefetch: issue->use distance = one 48-MFMA cluster
            if (ks < 7) loadB(nxt, ccr, ks + 1);
            else if (cc < 3) loadB(nxt, ccn, 0);   // also covered by chunk epilogue
            __builtin_amdgcn_sched_barrier(0);

            __builtin_amdgcn_s_setprio(1);
            // 16 independent acc chains, 48 MFMA
#pragma unroll
            for (int m = 0; m < 4; ++m)
#pragma unroll
                for (int n = 0; n < 2; ++n)
                    accC[m][n] = __builtin_amdgcn_mfma_f32_16x16x32_f16(aH[m], B[cur][n * 2], accC[m][n], 0, 0, 0);
#pragma unroll
            for (int m = 0; m < 4; ++m)
#pragma unroll
                for (int n = 0; n < 2; ++n)
                    accP[m][n] = __builtin_amdgcn_mfma_f32_16x16x32_f16(aH[m], B[cur][4 + n * 2], accP[m][n], 0, 0, 0);
#pragma unroll
            for (int m = 0; m < 4; ++m)
#pragma unroll
                for (int n = 0; n < 2; ++n)
                    accC[m][n] = __builtin_amdgcn_mfma_f32_16x16x32_f16(aH[m], B[cur][n * 2 + 1], accC[m][n], 0, 0, 0);
#pragma unroll
            for (int m = 0; m < 4; ++m)
#pragma unroll
                for (int n = 0; n < 2; ++n)
                    accP[m][n] = __builtin_amdgcn_mfma_f32_16x16x32_f16(aH[m], B[cur][4 + n * 2 + 1], accP[m][n], 0, 0, 0);
#pragma unroll
            for (int m = 0; m < 4; ++m)
#pragma unroll
                for (int n = 0; n < 2; ++n)
                    accC[m][n] = __builtin_amdgcn_mfma_f32_16x16x32_f16(aL[m], B[cur][n * 2], accC[m][n], 0, 0, 0);
#pragma unroll
            for (int m = 0; m < 4; ++m)
#pragma unroll
                for (int n = 0; n < 2; ++n)
                    accP[m][n] = __builtin_amdgcn_mfma_f32_16x16x32_f16(aL[m], B[cur][4 + n * 2], accP[m][n], 0, 0, 0);
            __builtin_amdgcn_s_setprio(0);
        }

        // ---- per-chunk epilogue: w = __expf, cos via v_fract+v_cos (revolutions) ----
#pragma unroll
        for (int m = 0; m < 4; ++m)
#pragma unroll
            for (int n = 0; n < 2; ++n) {
                const int col = wc * 128 + ccr * 32 + n * 16 + lr;
                const float msq = musq[col], il2 = inv2s2[col], prv = phirev[col];
                f32x4 ccv = accC[m][n], pp = accP[m][n];
#pragma unroll
                for (int rg = 0; rg < 4; ++rg) {
                    const int rowl = m * 16 + lg * 4 + rg;
                    float dsq = fmaxf(sZsq[rowl] + msq - 2.0f * ccv[rg], 0.f);
                    float w = __expf(-dsq * il2);
                    float ph = __builtin_fmaf(pp[rg], INV2PI, prv);
                    float r, cs;
                    asm("v_fract_f32 %0, %1" : "=v"(r) : "v"(ph));
                    asm("v_cos_f32 %0, %1" : "=v"(cs) : "v"(r));
                    out[(size_t)(rbase + rowl) * R_DIM + col] = w * cs;
                    rs[m * 4 + rg] += w;
                }
            }
    }

    // ---- block-local row sums -> normalize own 64x1024 tile ----
#pragma unroll
    for (int i = 0; i < 16; ++i) {
#pragma unroll
        for (int sh = 1; sh < 16; sh <<= 1) rs[i] += __shfl_xor(rs[i], sh, 64);
    }
    if (lr == 0) {
#pragma unroll
        for (int m = 0; m < 4; ++m)
#pragma unroll
            for (int rg = 0; rg < 4; ++rg)
                sRow[wc][m * 16 + lg * 4 + rg] = rs[m * 4 + rg];
    }
    __syncthreads();
    if (tid < 64) {
        float s = 0.f;
#pragma unroll
        for (int w8 = 0; w8 < 8; ++w8) s += sRow[w8][tid];
        sInvN[tid] = 1.0f / fmaxf(s, 1e-6f);
    }
    __threadfence_block();
    __syncthreads();

    float4* obase = (float4*)(out + (size_t)rbase * R_DIM);
#pragma unroll 4
    for (int j = 0; j < 32; ++j) {
        const int idx = j * 512 + tid;        // 0..16383 float4s
        const int row = idx >> 8, c4 = idx & 255;
        const float inv = sInvN[row];
        float4 v = obase[row * 256 + c4];
        v.x *= inv; v.y *= inv; v.z *= inv; v.w *= inv;
        obase[row * 256 + c4] = v;
    }
}

extern "C" void kernel_launch(void* const* d_in, const int* in_sizes, int n_in,
                              void* d_out, int out_size, void* d_ws, size_t ws_size,
                              hipStream_t stream) {
    const float* z    = (const float*)d_in[0];
    const float* mu   = (const float*)d_in[1];
    const float* Kmat = (const float*)d_in[2];
    const float* ls   = (const float*)d_in[3];
    const float* phi  = (const float*)d_in[4];
    float* out = (float*)d_out;
    float* ws = (float*)d_ws;
    float* zsq      = ws;                        // 16384
    float* musq     = ws + 16384;                // 1024
    float* i2s      = ws + 17408;                // 1024
    float* phirev   = ws + 18432;                // 1024
    _Float16* muf = (_Float16*)(ws + 150528);    // 1024*512 halves (16x16 fragment order)
    _Float16* kf  = muf + 524288;                // 1024*512
    const bool pre = ws_size >= 2700000ull;      // floats + 2x1MB fragment buffers

    // one fused prep kernel: zsq + mu stats (+ fragment split when pre)
    hipLaunchKernelGGL(gabor_prep, dim3(pre ? 4608 : 4352), dim3(256), 0, stream,
                       z, mu, Kmat, ls, phi, zsq, musq, i2s, phirev, muf, kf);
    if (pre) {
        hipLaunchKernelGGL(gabor_main<true>, dim3(M_DIM / 64), dim3(512), 0, stream,
                           z, mu, Kmat, muf, kf, zsq, musq, i2s, phirev, out);
    } else {
        hipLaunchKernelGGL(gabor_main<false>, dim3(M_DIM / 64), dim3(512), 0, stream,
                           z, mu, Kmat, muf, kf, zsq, musq, i2s, phirev, out);
    }
}

// Round 20
// 75.765 us; speedup vs baseline: 1.0587x; 1.0119x over previous
//
#include <hip/hip_runtime.h>

// GaborBasis: out[b,t,r] = window_norm * cos(z·K[r] + phi[r]),
//   window = exp(-max(|z|^2+|mu_r|^2-2 z·mu_r,0)/(2 sigma_r^2)), normalized over r.
// fp16 hi/lo 3-term split MFMA (16x16x32); v_fract+v_cos epilogue.
// Round 20: 12 main-loop variants all plateau at ~68.6us with all pipes <=34%
// (documented plain-HIP schedule plateau, ~36% of f16 MFMA ceiling). Remaining
// cheap win is OUTSIDE the loop: fuse the zsq pass into main's A-staging
// (prep's 4096-block pass re-read all 16.8MB of z that main loads anyway).
// Prep is now mu-stats + fragment split only (~1.5us). Main loop = r17 verbatim.

typedef _Float16 f16x8 __attribute__((ext_vector_type(8)));
typedef float f32x4 __attribute__((ext_vector_type(4)));

#define M_DIM 16384
#define R_DIM 1024
#define INV2PI 0.15915494309189535f

// ---------------- prep: mu stats (blocks 0..255) + mu/K fragment split (256..511) ----------------
__global__ void gabor_prep(const float* __restrict__ mu, const float* __restrict__ Kmat,
                           const float* __restrict__ ls, const float* __restrict__ phi,
                           float* __restrict__ musq, float* __restrict__ inv2s2,
                           float* __restrict__ phirev,
                           _Float16* __restrict__ muf, _Float16* __restrict__ kf) {
    const int bid = blockIdx.x;
    if (bid < 256) {
        const int lane = threadIdx.x & 63;
        const int wv = threadIdx.x >> 6;
        const int row = bid * 4 + wv;               // 0..1023
        float4 v = *(const float4*)(mu + (size_t)row * 256 + lane * 4);
        float s = v.x * v.x + v.y * v.y + v.z * v.z + v.w * v.w;
#pragma unroll
        for (int sh = 1; sh < 64; sh <<= 1) s += __shfl_xor(s, sh, 64);
        if (lane == 0) {
            musq[row] = s;
            float e = expf(ls[row]);
            inv2s2[row] = 1.0f / (2.0f * (e * e + 1e-8f));
            phirev[row] = phi[row] * INV2PI;
        }
        return;
    }
    // fragment split: 16x16x32 MFMA order. Per matrix: [sub=col/16][ks=k/32] x 1024
    // halves: hi at lane*8, lo at 512+lane*8, lane = (col&15) | ((k>>3 & 3)<<4).
    const int t = (bid - 256) * 256 + threadIdx.x;   // 0..65535
    const float* src; _Float16* dst; int item;
    if (t < 32768) { item = t;          src = mu;   dst = muf; }
    else           { item = t - 32768;  src = Kmat; dst = kf; }
    const int sub = item >> 9, rem = item & 511;      // sub 0..63
    const int ks = rem >> 6, l = rem & 63;
    const int col = sub * 16 + (l & 15);
    const int k0 = ks * 32 + (l >> 4) * 8;
    const float* sp = src + (size_t)col * 256 + k0;
    float v[8];
    *(float4*)&v[0] = *(const float4*)(sp);
    *(float4*)&v[4] = *(const float4*)(sp + 4);
    f16x8 hi, lo;
#pragma unroll
    for (int j = 0; j < 8; ++j) {
        _Float16 h = (_Float16)v[j];
        hi[j] = h;
        lo[j] = (_Float16)(v[j] - (float)h);
    }
    _Float16* d = dst + (size_t)(sub * 8 + ks) * 1024;
    *(f16x8*)(d + l * 8) = hi;
    *(f16x8*)(d + 512 + l * 8) = lo;
}

// ---------------- main: 256 blocks x 512 thr (8 waves). Block = 64 rows x 1024 cols. ----------------
// Wave = all 64 rows x disjoint 128-col slice; 4 chunks of 32 cols (rotated per
// block); 48-MFMA clusters; barrier-free K loop; block-local normalization.
// zsq computed in-block during A staging (shfl fold + 512 LDS atomics).
template <bool PRE>
__global__ __launch_bounds__(512, 2) void gabor_main(
    const float* __restrict__ z, const float* __restrict__ mu, const float* __restrict__ Kmat,
    const _Float16* __restrict__ muf, const _Float16* __restrict__ kf,
    const float* __restrict__ musq, const float* __restrict__ inv2s2,
    const float* __restrict__ phirev, float* __restrict__ out) {
    __shared__ _Float16 sA[32768];      // [sub 0..3][ks 0..7][1024]: hi lane*8, lo 512+lane*8 (64KB)
    __shared__ float sZsq[64];
    __shared__ float sRow[8][64];
    __shared__ float sInvN[64];

    const int tid = threadIdx.x;
    const int bid = blockIdx.x;
    const int rbase = bid * 64;
    const int lane = tid & 63;
    const int wc = tid >> 6;               // 0..7 : this wave's 128-col slice (disjoint)
    const int lr = lane & 15, lg = lane >> 4;

    if (tid < 64) sZsq[tid] = 0.f;
    __syncthreads();

    // ---- stage A panel (64 rows x 256 k, hi/lo) ONCE, from raw fp32 z;
    //      accumulate zsq on the fly ----
    float zacc[4];
#pragma unroll
    for (int j = 0; j < 4; ++j) {
        const int it = tid + j * 512;        // 0..2047: sub(4) x ks(8) x lane(64)
        const int sub = it >> 9, rem = it & 511;
        const int ks = rem >> 6, l = rem & 63;
        const int row = rbase + sub * 16 + (l & 15);
        const float* sp = z + (size_t)row * 256 + ks * 32 + (l >> 4) * 8;
        float v[8];
        *(float4*)&v[0] = *(const float4*)(sp);
        *(float4*)&v[4] = *(const float4*)(sp + 4);
        f16x8 hi, lo;
        float s = 0.f;
#pragma unroll
        for (int q = 0; q < 8; ++q) {
            _Float16 h = (_Float16)v[q];
            hi[q] = h; lo[q] = (_Float16)(v[q] - (float)h);
            s = __builtin_fmaf(v[q], v[q], s);
        }
        zacc[j] = s;
        const int o = (sub * 8 + ks) * 1024 + l * 8;
        *(f16x8*)&sA[o] = hi;
        *(f16x8*)&sA[o + 512] = lo;
    }
    // fold the 4 k-granules (lanes l, l^16, l^32, l^48) sharing each row,
    // then one atomicAdd per wave-row merges the 8 waves' k-chunks.
#pragma unroll
    for (int j = 0; j < 4; ++j) {
        zacc[j] += __shfl_xor(zacc[j], 16, 64);
        zacc[j] += __shfl_xor(zacc[j], 32, 64);
    }
    if (lg == 0) {
#pragma unroll
        for (int j = 0; j < 4; ++j)
            atomicAdd(&sZsq[j * 16 + lr], zacc[j]);
    }
    __syncthreads();                       // staging + zsq complete

    float rs[16];
#pragma unroll
    for (int i = 0; i < 16; ++i) rs[i] = 0.f;

    // B register sets: [mu0H, mu0L, mu1H, mu1L, k0H, k0L, k1H, k1L] x2 (ping-pong)
    f16x8 B[2][8];
    auto loadB = [&](int buf, int cc, int ks) {
        if constexpr (PRE) {
            const size_t sb = (size_t)((wc * 8 + cc * 2) * 8 + ks) * 1024 + lane * 8;
            const _Float16* mp = muf + sb;
            B[buf][0] = *(const f16x8*)(mp);
            B[buf][1] = *(const f16x8*)(mp + 512);
            B[buf][2] = *(const f16x8*)(mp + 8192);
            B[buf][3] = *(const f16x8*)(mp + 8192 + 512);
            const _Float16* kp = kf + sb;
            B[buf][4] = *(const f16x8*)(kp);
            B[buf][5] = *(const f16x8*)(kp + 512);
            B[buf][6] = *(const f16x8*)(kp + 8192);
            B[buf][7] = *(const f16x8*)(kp + 8192 + 512);
        } else {
#pragma unroll
            for (int n = 0; n < 2; ++n) {
                const int col = wc * 128 + cc * 32 + n * 16 + lr;
                const int k0 = ks * 32 + lg * 8;
                float v[8];
                const float* sp = mu + (size_t)col * 256 + k0;
                *(float4*)&v[0] = *(const float4*)(sp);
                *(float4*)&v[4] = *(const float4*)(sp + 4);
#pragma unroll
                for (int q = 0; q < 8; ++q) {
                    _Float16 h = (_Float16)v[q];
                    B[buf][n * 2][q] = h; B[buf][n * 2 + 1][q] = (_Float16)(v[q] - (float)h);
                }
                const float* sp2 = Kmat + (size_t)col * 256 + k0;
                *(float4*)&v[0] = *(const float4*)(sp2);
                *(float4*)&v[4] = *(const float4*)(sp2 + 4);
#pragma unroll
                for (int q = 0; q < 8; ++q) {
                    _Float16 h = (_Float16)v[q];
                    B[buf][4 + n * 2][q] = h; B[buf][4 + n * 2 + 1][q] = (_Float16)(v[q] - (float)h);
                }
            }
        }
    };

    // chunk order rotated per block (neutral but harmless)
    const int crot = bid & 3;
    loadB(0, crot, 0);

#pragma unroll 1
    for (int cc = 0; cc < 4; ++cc) {
        const int ccr = (cc + crot) & 3;
        const int ccn = (cc + 1 + crot) & 3;
        f32x4 accC[4][2], accP[4][2];
#pragma unroll
        for (int m = 0; m < 4; ++m)
#pragma unroll
            for (int n = 0; n < 2; ++n) {
                accC[m][n] = (f32x4){0.f, 0.f, 0.f, 0.f};
                accP[m][n] = (f32x4){0.f, 0.f, 0.f, 0.f};
            }

#pragma unroll
        for (int ks = 0; ks < 8; ++ks) {
            const int cur = ks & 1;
            const int nxt = cur ^ 1;
            // A fragments from LDS: all 4 row-subs (lane-linear, conflict-free)
            f16x8 aH[4], aL[4];
#pragma unroll
            for (int m = 0; m < 4; ++m) {
                const int o = (m * 8 + ks) * 1024 + lane * 8;
                aH[m] = *(const f16x8*)&sA[o];
                aL[m] = *(const f16x8*)&sA[o + 512];
            }
            // ping-pong B prefetch: issue->use distance = one 48-MFMA cluster
            if (ks < 7) loadB(nxt, ccr, ks + 1);
            else if (cc < 3) loadB(nxt, ccn, 0);   // also covered by chunk epilogue
            __builtin_amdgcn_sched_barrier(0);

            __builtin_amdgcn_s_setprio(1);
            // 16 independent acc chains, 48 MFMA
#pragma unroll
            for (int m = 0; m < 4; ++m)
#pragma unroll
                for (int n = 0; n < 2; ++n)
                    accC[m][n] = __builtin_amdgcn_mfma_f32_16x16x32_f16(aH[m], B[cur][n * 2], accC[m][n], 0, 0, 0);
#pragma unroll
            for (int m = 0; m < 4; ++m)
#pragma unroll
                for (int n = 0; n < 2; ++n)
                    accP[m][n] = __builtin_amdgcn_mfma_f32_16x16x32_f16(aH[m], B[cur][4 + n * 2], accP[m][n], 0, 0, 0);
#pragma unroll
            for (int m = 0; m < 4; ++m)
#pragma unroll
                for (int n = 0; n < 2; ++n)
                    accC[m][n] = __builtin_amdgcn_mfma_f32_16x16x32_f16(aH[m], B[cur][n * 2 + 1], accC[m][n], 0, 0, 0);
#pragma unroll
            for (int m = 0; m < 4; ++m)
#pragma unroll
                for (int n = 0; n < 2; ++n)
                    accP[m][n] = __builtin_amdgcn_mfma_f32_16x16x32_f16(aH[m], B[cur][4 + n * 2 + 1], accP[m][n], 0, 0, 0);
#pragma unroll
            for (int m = 0; m < 4; ++m)
#pragma unroll
                for (int n = 0; n < 2; ++n)
                    accC[m][n] = __builtin_amdgcn_mfma_f32_16x16x32_f16(aL[m], B[cur][n * 2], accC[m][n], 0, 0, 0);
#pragma unroll
            for (int m = 0; m < 4; ++m)
#pragma unroll
                for (int n = 0; n < 2; ++n)
                    accP[m][n] = __builtin_amdgcn_mfma_f32_16x16x32_f16(aL[m], B[cur][4 + n * 2], accP[m][n], 0, 0, 0);
            __builtin_amdgcn_s_setprio(0);
        }

        // ---- per-chunk epilogue: w = __expf, cos via v_fract+v_cos (revolutions) ----
#pragma unroll
        for (int m = 0; m < 4; ++m)
#pragma unroll
            for (int n = 0; n < 2; ++n) {
                const int col = wc * 128 + ccr * 32 + n * 16 + lr;
                const float msq = musq[col], il2 = inv2s2[col], prv = phirev[col];
                f32x4 ccv = accC[m][n], pp = accP[m][n];
#pragma unroll
                for (int rg = 0; rg < 4; ++rg) {
                    const int rowl = m * 16 + lg * 4 + rg;
                    float dsq = fmaxf(sZsq[rowl] + msq - 2.0f * ccv[rg], 0.f);
                    float w = __expf(-dsq * il2);
                    float ph = __builtin_fmaf(pp[rg], INV2PI, prv);
                    float r, cs;
                    asm("v_fract_f32 %0, %1" : "=v"(r) : "v"(ph));
                    asm("v_cos_f32 %0, %1" : "=v"(cs) : "v"(r));
                    out[(size_t)(rbase + rowl) * R_DIM + col] = w * cs;
                    rs[m * 4 + rg] += w;
                }
            }
    }

    // ---- block-local row sums -> normalize own 64x1024 tile ----
#pragma unroll
    for (int i = 0; i < 16; ++i) {
#pragma unroll
        for (int sh = 1; sh < 16; sh <<= 1) rs[i] += __shfl_xor(rs[i], sh, 64);
    }
    if (lr == 0) {
#pragma unroll
        for (int m = 0; m < 4; ++m)
#pragma unroll
            for (int rg = 0; rg < 4; ++rg)
                sRow[wc][m * 16 + lg * 4 + rg] = rs[m * 4 + rg];
    }
    __syncthreads();
    if (tid < 64) {
        float s = 0.f;
#pragma unroll
        for (int w8 = 0; w8 < 8; ++w8) s += sRow[w8][tid];
        sInvN[tid] = 1.0f / fmaxf(s, 1e-6f);
    }
    __threadfence_block();
    __syncthreads();

    float4* obase = (float4*)(out + (size_t)rbase * R_DIM);
#pragma unroll 4
    for (int j = 0; j < 32; ++j) {
        const int idx = j * 512 + tid;        // 0..16383 float4s
        const int row = idx >> 8, c4 = idx & 255;
        const float inv = sInvN[row];
        float4 v = obase[row * 256 + c4];
        v.x *= inv; v.y *= inv; v.z *= inv; v.w *= inv;
        obase[row * 256 + c4] = v;
    }
}

extern "C" void kernel_launch(void* const* d_in, const int* in_sizes, int n_in,
                              void* d_out, int out_size, void* d_ws, size_t ws_size,
                              hipStream_t stream) {
    const float* z    = (const float*)d_in[0];
    const float* mu   = (const float*)d_in[1];
    const float* Kmat = (const float*)d_in[2];
    const float* ls   = (const float*)d_in[3];
    const float* phi  = (const float*)d_in[4];
    float* out = (float*)d_out;
    float* ws = (float*)d_ws;
    float* musq     = ws + 16384;                // 1024  (layout kept from r17)
    float* i2s      = ws + 17408;                // 1024
    float* phirev   = ws + 18432;                // 1024
    _Float16* muf = (_Float16*)(ws + 150528);    // 1024*512 halves (16x16 fragment order)
    _Float16* kf  = muf + 524288;                // 1024*512
    const bool pre = ws_size >= 2700000ull;      // floats + 2x1MB fragment buffers

    // prep: mu stats (+ fragment split when pre); zsq is fused into gabor_main
    hipLaunchKernelGGL(gabor_prep, dim3(pre ? 512 : 256), dim3(256), 0, stream,
                       mu, Kmat, ls, phi, musq, i2s, phirev, muf, kf);
    if (pre) {
        hipLaunchKernelGGL(gabor_main<true>, dim3(M_DIM / 64), dim3(512), 0, stream,
                           z, mu, Kmat, muf, kf, musq, i2s, phirev, out);
    } else {
        hipLaunchKernelGGL(gabor_main<false>, dim3(M_DIM / 64), dim3(512), 0, stream,
                           z, mu, Kmat, muf, kf, musq, i2s, phirev, out);
    }
}